// Round 7
// baseline (781.298 us; speedup 1.0000x reference)
//
#include <hip/hip_runtime.h>
#include <math.h>

typedef __attribute__((ext_vector_type(8))) short short8;
typedef __attribute__((ext_vector_type(4))) float floatx4;

__device__ __forceinline__ float b2f(ushort u) {
    union { uint i; float f; } c; c.i = ((uint)u) << 16; return c.f;
}
__device__ __forceinline__ ushort f2b(float f) {
    union { float f; uint i; } c; c.f = f;
    return (ushort)((c.i + 0x7fffu + ((c.i >> 16) & 1u)) >> 16);
}

__device__ __forceinline__ void async_cp16(const ushort* g, ushort* l) {
    __builtin_amdgcn_global_load_lds(
        (const __attribute__((address_space(1))) void*)g,
        (__attribute__((address_space(3))) void*)l, 16, 0, 0);
}

// max-reduce over the 16-lane DPP row using full-rate VALU DPP ops
__device__ __forceinline__ float dpp_max16(float x) {
    int y;
    y = __builtin_amdgcn_update_dpp(__float_as_int(x), __float_as_int(x), 0xB1, 0xF, 0xF, false);
    x = fmaxf(x, __int_as_float(y));
    y = __builtin_amdgcn_update_dpp(__float_as_int(x), __float_as_int(x), 0x4E, 0xF, 0xF, false);
    x = fmaxf(x, __int_as_float(y));
    y = __builtin_amdgcn_update_dpp(__float_as_int(x), __float_as_int(x), 0x141, 0xF, 0xF, false);
    x = fmaxf(x, __int_as_float(y));
    y = __builtin_amdgcn_update_dpp(__float_as_int(x), __float_as_int(x), 0x140, 0xF, 0xF, false);
    x = fmaxf(x, __int_as_float(y));
    return x;
}

// ---------------- fp32 [K,N] -> bf16 transposed [N,K] ----------------
__global__ __launch_bounds__(256) void cvt_t_kernel(
    const float* __restrict__ S, ushort* __restrict__ D, int K, int N)
{
    __shared__ float ls[32][33];
    const int k0 = blockIdx.y * 32, n0 = blockIdx.x * 32;
    const int t = threadIdx.x;
    const int kr = t >> 3, nc = (t & 7) * 4;
    float4 f = *(const float4*)(S + (size_t)(k0 + kr) * N + n0 + nc);
    ls[kr][nc] = f.x; ls[kr][nc + 1] = f.y; ls[kr][nc + 2] = f.z; ls[kr][nc + 3] = f.w;
    __syncthreads();
    const int nr = t >> 3, kc = (t & 7) * 4;
    ushort4 o;
    o.x = f2b(ls[kc][nr]); o.y = f2b(ls[kc + 1][nr]);
    o.z = f2b(ls[kc + 2][nr]); o.w = f2b(ls[kc + 3][nr]);
    *(ushort4*)(D + (size_t)(n0 + nr) * K + k0 + kc) = o;
}

// ---------------- LayerNorm: fp32 in, bf16 out ----------------
__global__ __launch_bounds__(256) void ln_kernel(
    const float* __restrict__ X, const float* __restrict__ G,
    const float* __restrict__ Bb, ushort* __restrict__ Y)
{
    const int row = blockIdx.x;
    const int t = threadIdx.x;
    const float* xr = X + (size_t)row * 1024;
    float4 p = ((const float4*)xr)[t];
    float s = p.x + p.y + p.z + p.w;
    float s2 = p.x * p.x + p.y * p.y + p.z * p.z + p.w * p.w;
    #pragma unroll
    for (int off = 32; off > 0; off >>= 1) {
        s += __shfl_down(s, off);
        s2 += __shfl_down(s2, off);
    }
    __shared__ float rs1[4], rs2[4];
    if ((t & 63) == 0) { rs1[t >> 6] = s; rs2[t >> 6] = s2; }
    __syncthreads();
    float S1 = rs1[0] + rs1[1] + rs1[2] + rs1[3];
    float S2 = rs2[0] + rs2[1] + rs2[2] + rs2[3];
    float mu = S1 * (1.0f / 1024.0f);
    float var = S2 * (1.0f / 1024.0f) - mu * mu;
    float rstd = rsqrtf(var + 1e-12f);
    float4 gp = ((const float4*)G)[t];
    float4 bp = ((const float4*)Bb)[t];
    ushort4 o;
    o.x = f2b((p.x - mu) * rstd * gp.x + bp.x);
    o.y = f2b((p.y - mu) * rstd * gp.y + bp.y);
    o.z = f2b((p.z - mu) * rstd * gp.z + bp.z);
    o.w = f2b((p.w - mu) * rstd * gp.w + bp.w);
    ((ushort4*)(Y + (size_t)row * 1024))[t] = o;
}

// ---------------- GEMM (B^T form, m97 structure): C[M,N] = A[M,K] @ Bt[N,K]^T
template<int BN, bool BIAS, bool SILU, bool RESID, bool OUTF32>
__global__ __launch_bounds__(256) void gemm_bt_kernel(
    const ushort* __restrict__ A, const ushort* __restrict__ Bt,
    const float* __restrict__ bias, const float* __restrict__ resid,
    void* __restrict__ Cm, int M, int N, int K)
{
    constexpr int NF = BN / 32;
    constexpr int BI = BN / 64;
    __shared__ __align__(16) ushort lsA[128 * 32];
    __shared__ __align__(16) ushort lsB[BN * 32];

    const int t = threadIdx.x;
    const int m0 = blockIdx.y * 128;
    const int n0 = blockIdx.x * BN;
    const int w = t >> 6;
    const int lane = t & 63;
    const int wm = (w >> 1) * 64;
    const int wn = (w & 1) * (BN / 2);
    const int quad = lane >> 4;
    const int l16 = lane & 15;
    const int ko = quad * 8;

    const int lrow = lane >> 2;
    const int scol = (lane & 3) * 8;
    const int srA = w * 32 + lrow;
    const int srB = (BI == 2) ? (w * 32 + lrow) : (w * 16 + lrow);
    const ushort* gA = A + (size_t)(m0 + srA) * K + scol;
    const ushort* gB = Bt + (size_t)(n0 + srB) * K + scol;
    ushort* lA0 = &lsA[(w * 32) * 32];
    ushort* lA1 = &lsA[(w * 32 + 16) * 32];
    ushort* lB0 = (BI == 2) ? &lsB[(w * 32) * 32] : &lsB[(w * 16) * 32];
    ushort* lB1 = (BI == 2) ? &lsB[(w * 32 + 16) * 32] : nullptr;

    floatx4 acc[4][NF];
    #pragma unroll
    for (int i = 0; i < 4; ++i)
        #pragma unroll
        for (int j = 0; j < NF; ++j)
            acc[i][j] = (floatx4){0.f, 0.f, 0.f, 0.f};

    for (int k0 = 0; k0 < K; k0 += 32) {
        __syncthreads();
        async_cp16(gA + k0, lA0);
        async_cp16(gA + (size_t)16 * K + k0, lA1);
        async_cp16(gB + k0, lB0);
        if constexpr (BI == 2) async_cp16(gB + (size_t)16 * K + k0, lB1);
        __syncthreads();

        short8 af[4], bf[NF];
        #pragma unroll
        for (int i = 0; i < 4; ++i)
            af[i] = *(const short8*)&lsA[(wm + i * 16 + l16) * 32 + ko];
        #pragma unroll
        for (int j = 0; j < NF; ++j)
            bf[j] = *(const short8*)&lsB[(wn + j * 16 + l16) * 32 + ko];
        #pragma unroll
        for (int i = 0; i < 4; ++i)
            #pragma unroll
            for (int j = 0; j < NF; ++j)
                acc[i][j] = __builtin_amdgcn_mfma_f32_16x16x32_bf16(
                    af[i], bf[j], acc[i][j], 0, 0, 0);
    }

    #pragma unroll
    for (int tn = 0; tn < NF; ++tn) {
        const int n = n0 + wn + tn * 16 + l16;
        const float bv = BIAS ? bias[n] : 0.0f;
        #pragma unroll
        for (int tm = 0; tm < 4; ++tm) {
            const int mbase = m0 + wm + tm * 16 + quad * 4;
            #pragma unroll
            for (int rr = 0; rr < 4; ++rr) {
                float v = acc[tm][tn][rr] + bv;
                if (SILU) v = v / (1.0f + __expf(-v));
                const size_t off = (size_t)(mbase + rr) * N + n;
                if (RESID) v += resid[off];
                if constexpr (OUTF32) ((float*)Cm)[off] = v;
                else                  ((ushort*)Cm)[off] = f2b(v);
            }
        }
    }
}

// ---------------- MFMA flash attention, 128 queries/block ----------------
// grid (S/128, B*H), block 256 (4 waves). Wave w owns 32 queries = 2 strips
// of 16. Q-LDS aliased with P (Q consumed to registers before first P write).
// Softmax in exp2 domain; additive pad-mask bias; causal selects only in
// diagonal-overlapping tiles; per-strip skip of fully-masked tiles.
__global__ __launch_bounds__(256) void attn_kernel(
    const ushort* __restrict__ Qm, const ushort* __restrict__ Km,
    const ushort* __restrict__ Vm, const int* __restrict__ amask,
    ushort* __restrict__ Om, int rs)
{
    __shared__ __align__(16) ushort lsQP[128][72];  // Q staging, then P strips
    __shared__ __align__(16) ushort lsK[64][72];
    __shared__ __align__(16) ushort lsVt[64][72];   // [dim][key]
    __shared__ int lsMk[64];

    const int qb = gridDim.x - 1 - blockIdx.x;      // heaviest first
    const int bh = blockIdx.y;
    const int b = bh >> 4, h = bh & 15;
    const int t = threadIdx.x;
    const int w = t >> 6, lane = t & 63;
    const int quad = lane >> 4, l16 = lane & 15;

    const int q0 = qb * 128;
    const size_t base = ((size_t)b * 2048) * rs + (size_t)h * 64;
    const size_t obase = ((size_t)b * 2048) * 1024 + (size_t)h * 64;

    // stage Q tile (128 x 64)
    #pragma unroll
    for (int it = 0; it < 4; ++it) {
        int idx = it * 256 + t;
        int row = idx >> 3, c8 = (idx & 7) << 3;
        *(int4*)&lsQP[row][c8] =
            *(const int4*)(Qm + base + (size_t)(q0 + row) * rs + c8);
    }
    __syncthreads();

    short8 aq[2][2];
    #pragma unroll
    for (int s = 0; s < 2; ++s) {
        aq[s][0] = *(const short8*)&lsQP[w * 32 + s * 16 + l16][quad * 8];
        aq[s][1] = *(const short8*)&lsQP[w * 32 + s * 16 + l16][32 + quad * 8];
    }

    short8 ones8;
    #pragma unroll
    for (int i = 0; i < 8; ++i) ones8[i] = (short)0x3F80;  // bf16 1.0

    floatx4 Oacc[2][4];
    floatx4 Lacc[2];
    float m_i[2][4];
    #pragma unroll
    for (int s = 0; s < 2; ++s) {
        Lacc[s] = (floatx4){0.f, 0.f, 0.f, 0.f};
        #pragma unroll
        for (int d = 0; d < 4; ++d) Oacc[s][d] = (floatx4){0.f, 0.f, 0.f, 0.f};
        #pragma unroll
        for (int rr = 0; rr < 4; ++rr) m_i[s][rr] = -INFINITY;
    }

    const int vp = t & 31;
    const int vc8 = (t >> 5) << 3;
    const int nkt = 2 * qb + 2;
    const float scale2 = 0.125f * 1.44269504f;   // softmax in exp2 domain

    for (int kt = 0; kt < nkt; ++kt) {
        const int k0 = kt * 64;
        __syncthreads();
        #pragma unroll
        for (int it = 0; it < 2; ++it) {
            int idx = it * 256 + t;
            int row = idx >> 3, c8 = (idx & 7) << 3;
            *(int4*)&lsK[row][c8] =
                *(const int4*)(Km + base + (size_t)(k0 + row) * rs + c8);
        }
        {
            int4 v0 = *(const int4*)(Vm + base + (size_t)(k0 + 2 * vp) * rs + vc8);
            int4 v1 = *(const int4*)(Vm + base + (size_t)(k0 + 2 * vp + 1) * rs + vc8);
            const ushort* p0 = (const ushort*)&v0;
            const ushort* p1 = (const ushort*)&v1;
            #pragma unroll
            for (int i = 0; i < 8; ++i) {
                uint pk = (uint)p0[i] | ((uint)p1[i] << 16);
                *(uint*)&lsVt[vc8 + i][2 * vp] = pk;
            }
        }
        if (t < 64) lsMk[t] = amask[b * 2048 + k0 + t];
        __syncthreads();

        const bool act0 = (k0 <= q0 + w * 32 + 15);
        const bool act1 = (k0 <= q0 + w * 32 + 31);
        if (!act1) continue;    // no valid keys for this wave; barriers at loop top

        float kb[4];
        #pragma unroll
        for (int j = 0; j < 4; ++j)
            kb[j] = (lsMk[j * 16 + l16] == 1) ? 0.f : -INFINITY;

        // ---- QK^T for both strips (shared B-frags) ----
        floatx4 sa[2][4];
        #pragma unroll
        for (int j = 0; j < 4; ++j) {
            short8 bk0 = *(const short8*)&lsK[j * 16 + l16][quad * 8];
            short8 bk1 = *(const short8*)&lsK[j * 16 + l16][32 + quad * 8];
            #pragma unroll
            for (int s = 0; s < 2; ++s) {
                floatx4 z = (floatx4){0.f, 0.f, 0.f, 0.f};
                z = __builtin_amdgcn_mfma_f32_16x16x32_bf16(aq[s][0], bk0, z, 0, 0, 0);
                sa[s][j] = __builtin_amdgcn_mfma_f32_16x16x32_bf16(aq[s][1], bk1, z, 0, 0, 0);
            }
        }

        // ---- online softmax per strip ----
        #pragma unroll
        for (int s = 0; s < 2; ++s) {
            const bool act = (s == 0) ? act0 : act1;
            if (!act) continue;
            const int strip_lo = q0 + w * 32 + s * 16;
            const bool caus = (k0 + 63 > strip_lo);
            float al[4], pj[4][4];
            #pragma unroll
            for (int rr = 0; rr < 4; ++rr) {
                const int qrow = strip_lo + quad * 4 + rr;
                float sv[4];
                float mxv = -INFINITY;
                #pragma unroll
                for (int j = 0; j < 4; ++j) {
                    float v = sa[s][j][rr] * scale2 + kb[j];
                    if (caus) v = (k0 + j * 16 + l16 <= qrow) ? v : -INFINITY;
                    sv[j] = v;
                    mxv = fmaxf(mxv, v);
                }
                mxv = dpp_max16(mxv);
                const float m_new = fmaxf(m_i[s][rr], mxv);
                al[rr] = exp2f(m_i[s][rr] - m_new);
                #pragma unroll
                for (int j = 0; j < 4; ++j) pj[j][rr] = exp2f(sv[j] - m_new);
                m_i[s][rr] = m_new;
            }
            #pragma unroll
            for (int rr = 0; rr < 4; ++rr) {
                #pragma unroll
                for (int d = 0; d < 4; ++d) Oacc[s][d][rr] *= al[rr];
                Lacc[s][rr] *= al[rr];
            }
            // P -> wave-private LDS strip (truncating bf16; error cancels in O/L)
            #pragma unroll
            for (int j = 0; j < 4; ++j)
                #pragma unroll
                for (int rr = 0; rr < 4; ++rr)
                    lsQP[w * 32 + s * 16 + quad * 4 + rr][j * 16 + l16] =
                        (ushort)(__float_as_uint(pj[j][rr]) >> 16);
        }

        // ---- PV + L (shared V B-frags) ----
        short8 ap[2][2];
        #pragma unroll
        for (int s = 0; s < 2; ++s) {
            const bool act = (s == 0) ? act0 : act1;
            if (!act) continue;
            ap[s][0] = *(const short8*)&lsQP[w * 32 + s * 16 + l16][quad * 8];
            ap[s][1] = *(const short8*)&lsQP[w * 32 + s * 16 + l16][32 + quad * 8];
        }
        #pragma unroll
        for (int d = 0; d < 4; ++d) {
            short8 bv0 = *(const short8*)&lsVt[d * 16 + l16][quad * 8];
            short8 bv1 = *(const short8*)&lsVt[d * 16 + l16][32 + quad * 8];
            #pragma unroll
            for (int s = 0; s < 2; ++s) {
                const bool act = (s == 0) ? act0 : act1;
                if (!act) continue;
                Oacc[s][d] = __builtin_amdgcn_mfma_f32_16x16x32_bf16(ap[s][0], bv0, Oacc[s][d], 0, 0, 0);
                Oacc[s][d] = __builtin_amdgcn_mfma_f32_16x16x32_bf16(ap[s][1], bv1, Oacc[s][d], 0, 0, 0);
            }
        }
        #pragma unroll
        for (int s = 0; s < 2; ++s) {
            const bool act = (s == 0) ? act0 : act1;
            if (!act) continue;
            Lacc[s] = __builtin_amdgcn_mfma_f32_16x16x32_bf16(ap[s][0], ones8, Lacc[s], 0, 0, 0);
            Lacc[s] = __builtin_amdgcn_mfma_f32_16x16x32_bf16(ap[s][1], ones8, Lacc[s], 0, 0, 0);
        }
    }

    // epilogue
    #pragma unroll
    for (int s = 0; s < 2; ++s)
        #pragma unroll
        for (int rr = 0; rr < 4; ++rr) {
            const float inv = 1.0f / Lacc[s][rr];
            const int row = q0 + w * 32 + s * 16 + quad * 4 + rr;
            ushort* op = Om + obase + (size_t)row * 1024;
            #pragma unroll
            for (int d = 0; d < 4; ++d)
                op[d * 16 + l16] = f2b(Oacc[s][d][rr] * inv);
        }
}

// ---------------- driver ----------------
// ws peak 72 MiB:
//   phase 1: xa [0,16) | qkvb [16,64) | Wqkv_t [64,70) | Wo_t [70,72)
//   phase 2: W1_t [0,8) W2_t [8,16) | yb [16,32) | hb chunk [32,64)
extern "C" void kernel_launch(void* const* d_in, const int* in_sizes, int n_in,
                              void* d_out, int out_size, void* d_ws, size_t ws_size,
                              hipStream_t stream) {
    const float* hidden = (const float*)d_in[0];
    const int*   amask  = (const int*)d_in[1];
    const float* Wq  = (const float*)d_in[2];
    const float* Wk  = (const float*)d_in[3];
    const float* Wv  = (const float*)d_in[4];
    const float* Wo  = (const float*)d_in[5];
    const float* l1g = (const float*)d_in[6];
    const float* l1b = (const float*)d_in[7];
    const float* W1  = (const float*)d_in[8];
    const float* b1  = (const float*)d_in[9];
    const float* W2  = (const float*)d_in[10];
    const float* b2  = (const float*)d_in[11];
    const float* l2g = (const float*)d_in[12];
    const float* l2b = (const float*)d_in[13];

    const int M = 8192;
    const size_t MB = 1048576;
    char* ws = (char*)d_ws;
    ushort* xa    = (ushort*)(ws);
    ushort* qkvb  = (ushort*)(ws + 16 * MB);
    ushort* Wqkvt = (ushort*)(ws + 64 * MB);
    ushort* Wot   = (ushort*)(ws + 70 * MB);
    ushort* W1t   = (ushort*)(ws);
    ushort* W2t   = (ushort*)(ws + 8 * MB);
    ushort* yb    = (ushort*)(ws + 16 * MB);
    ushort* hbc   = (ushort*)(ws + 32 * MB);
    float*  x2    = (float*)d_out;

    cvt_t_kernel<<<dim3(32, 32), 256, 0, stream>>>(Wq, Wqkvt, 1024, 1024);
    cvt_t_kernel<<<dim3(32, 32), 256, 0, stream>>>(Wk, Wqkvt + (size_t)1024 * 1024, 1024, 1024);
    cvt_t_kernel<<<dim3(32, 32), 256, 0, stream>>>(Wv, Wqkvt + (size_t)2048 * 1024, 1024, 1024);
    cvt_t_kernel<<<dim3(32, 32), 256, 0, stream>>>(Wo, Wot, 1024, 1024);

    ln_kernel<<<M, 256, 0, stream>>>(hidden, l1g, l1b, xa);
    gemm_bt_kernel<128, false, false, false, false><<<dim3(24, 64), 256, 0, stream>>>(
        xa, Wqkvt, nullptr, nullptr, qkvb, M, 3072, 1024);
    attn_kernel<<<dim3(16, 64), 256, 0, stream>>>(
        qkvb, qkvb + 1024, qkvb + 2048, amask, xa, 3072);
    gemm_bt_kernel<64, false, false, true, true><<<dim3(16, 64), 256, 0, stream>>>(
        xa, Wot, nullptr, hidden, x2, M, 1024, 1024);

    cvt_t_kernel<<<dim3(128, 32), 256, 0, stream>>>(W1, W1t, 1024, 4096);
    cvt_t_kernel<<<dim3(32, 128), 256, 0, stream>>>(W2, W2t, 4096, 1024);

    ln_kernel<<<M, 256, 0, stream>>>(x2, l2g, l2b, yb);
    for (int mc = 0; mc < 2; ++mc) {
        const size_t off = (size_t)mc * 4096 * 1024;
        gemm_bt_kernel<128, true, true, false, false><<<dim3(32, 32), 256, 0, stream>>>(
            yb + off, W1t, b1, nullptr, hbc, 4096, 4096, 1024);
        gemm_bt_kernel<64, true, false, true, true><<<dim3(16, 32), 256, 0, stream>>>(
            hbc, W2t, b2, x2 + off, (void*)(x2 + off), 4096, 1024, 4096);
    }
}

// Round 8
// 710.679 us; speedup vs baseline: 1.0994x; 1.0994x over previous
//
#include <hip/hip_runtime.h>
#include <math.h>

typedef __attribute__((ext_vector_type(8))) short short8;
typedef __attribute__((ext_vector_type(4))) float floatx4;

__device__ __forceinline__ float b2f(ushort u) {
    union { uint i; float f; } c; c.i = ((uint)u) << 16; return c.f;
}
__device__ __forceinline__ ushort f2b(float f) {
    union { float f; uint i; } c; c.f = f;
    return (ushort)((c.i + 0x7fffu + ((c.i >> 16) & 1u)) >> 16);
}

__device__ __forceinline__ void async_cp16(const ushort* g, ushort* l) {
    __builtin_amdgcn_global_load_lds(
        (const __attribute__((address_space(1))) void*)g,
        (__attribute__((address_space(3))) void*)l, 16, 0, 0);
}

// max-reduce over the 16-lane DPP row using full-rate VALU DPP ops
__device__ __forceinline__ float dpp_max16(float x) {
    int y;
    y = __builtin_amdgcn_update_dpp(__float_as_int(x), __float_as_int(x), 0xB1, 0xF, 0xF, false);
    x = fmaxf(x, __int_as_float(y));
    y = __builtin_amdgcn_update_dpp(__float_as_int(x), __float_as_int(x), 0x4E, 0xF, 0xF, false);
    x = fmaxf(x, __int_as_float(y));
    y = __builtin_amdgcn_update_dpp(__float_as_int(x), __float_as_int(x), 0x141, 0xF, 0xF, false);
    x = fmaxf(x, __int_as_float(y));
    y = __builtin_amdgcn_update_dpp(__float_as_int(x), __float_as_int(x), 0x140, 0xF, 0xF, false);
    x = fmaxf(x, __int_as_float(y));
    return x;
}

// ---------------- fp32 [K,N] -> bf16 transposed [N,K] ----------------
__global__ __launch_bounds__(256) void cvt_t_kernel(
    const float* __restrict__ S, ushort* __restrict__ D, int K, int N)
{
    __shared__ float ls[32][33];
    const int k0 = blockIdx.y * 32, n0 = blockIdx.x * 32;
    const int t = threadIdx.x;
    const int kr = t >> 3, nc = (t & 7) * 4;
    float4 f = *(const float4*)(S + (size_t)(k0 + kr) * N + n0 + nc);
    ls[kr][nc] = f.x; ls[kr][nc + 1] = f.y; ls[kr][nc + 2] = f.z; ls[kr][nc + 3] = f.w;
    __syncthreads();
    const int nr = t >> 3, kc = (t & 7) * 4;
    ushort4 o;
    o.x = f2b(ls[kc][nr]); o.y = f2b(ls[kc + 1][nr]);
    o.z = f2b(ls[kc + 2][nr]); o.w = f2b(ls[kc + 3][nr]);
    *(ushort4*)(D + (size_t)(n0 + nr) * K + k0 + kc) = o;
}

// ---------------- LayerNorm: fp32 in, bf16 out ----------------
__global__ __launch_bounds__(256) void ln_kernel(
    const float* __restrict__ X, const float* __restrict__ G,
    const float* __restrict__ Bb, ushort* __restrict__ Y)
{
    const int row = blockIdx.x;
    const int t = threadIdx.x;
    const float* xr = X + (size_t)row * 1024;
    float4 p = ((const float4*)xr)[t];
    float s = p.x + p.y + p.z + p.w;
    float s2 = p.x * p.x + p.y * p.y + p.z * p.z + p.w * p.w;
    #pragma unroll
    for (int off = 32; off > 0; off >>= 1) {
        s += __shfl_down(s, off);
        s2 += __shfl_down(s2, off);
    }
    __shared__ float rs1[4], rs2[4];
    if ((t & 63) == 0) { rs1[t >> 6] = s; rs2[t >> 6] = s2; }
    __syncthreads();
    float S1 = rs1[0] + rs1[1] + rs1[2] + rs1[3];
    float S2 = rs2[0] + rs2[1] + rs2[2] + rs2[3];
    float mu = S1 * (1.0f / 1024.0f);
    float var = S2 * (1.0f / 1024.0f) - mu * mu;
    float rstd = rsqrtf(var + 1e-12f);
    float4 gp = ((const float4*)G)[t];
    float4 bp = ((const float4*)Bb)[t];
    ushort4 o;
    o.x = f2b((p.x - mu) * rstd * gp.x + bp.x);
    o.y = f2b((p.y - mu) * rstd * gp.y + bp.y);
    o.z = f2b((p.z - mu) * rstd * gp.z + bp.z);
    o.w = f2b((p.w - mu) * rstd * gp.w + bp.w);
    ((ushort4*)(Y + (size_t)row * 1024))[t] = o;
}

// ---------------- GEMM (B^T form, m97 structure): C[M,N] = A[M,K] @ Bt[N,K]^T
template<int BN, bool BIAS, bool SILU, bool RESID, bool OUTF32>
__global__ __launch_bounds__(256) void gemm_bt_kernel(
    const ushort* __restrict__ A, const ushort* __restrict__ Bt,
    const float* __restrict__ bias, const float* __restrict__ resid,
    void* __restrict__ Cm, int M, int N, int K)
{
    constexpr int NF = BN / 32;
    constexpr int BI = BN / 64;
    __shared__ __align__(16) ushort lsA[128 * 32];
    __shared__ __align__(16) ushort lsB[BN * 32];

    const int t = threadIdx.x;
    const int m0 = blockIdx.y * 128;
    const int n0 = blockIdx.x * BN;
    const int w = t >> 6;
    const int lane = t & 63;
    const int wm = (w >> 1) * 64;
    const int wn = (w & 1) * (BN / 2);
    const int quad = lane >> 4;
    const int l16 = lane & 15;
    const int ko = quad * 8;

    const int lrow = lane >> 2;
    const int scol = (lane & 3) * 8;
    const int srA = w * 32 + lrow;
    const int srB = (BI == 2) ? (w * 32 + lrow) : (w * 16 + lrow);
    const ushort* gA = A + (size_t)(m0 + srA) * K + scol;
    const ushort* gB = Bt + (size_t)(n0 + srB) * K + scol;
    ushort* lA0 = &lsA[(w * 32) * 32];
    ushort* lA1 = &lsA[(w * 32 + 16) * 32];
    ushort* lB0 = (BI == 2) ? &lsB[(w * 32) * 32] : &lsB[(w * 16) * 32];
    ushort* lB1 = (BI == 2) ? &lsB[(w * 32 + 16) * 32] : nullptr;

    floatx4 acc[4][NF];
    #pragma unroll
    for (int i = 0; i < 4; ++i)
        #pragma unroll
        for (int j = 0; j < NF; ++j)
            acc[i][j] = (floatx4){0.f, 0.f, 0.f, 0.f};

    for (int k0 = 0; k0 < K; k0 += 32) {
        __syncthreads();
        async_cp16(gA + k0, lA0);
        async_cp16(gA + (size_t)16 * K + k0, lA1);
        async_cp16(gB + k0, lB0);
        if constexpr (BI == 2) async_cp16(gB + (size_t)16 * K + k0, lB1);
        __syncthreads();

        short8 af[4], bf[NF];
        #pragma unroll
        for (int i = 0; i < 4; ++i)
            af[i] = *(const short8*)&lsA[(wm + i * 16 + l16) * 32 + ko];
        #pragma unroll
        for (int j = 0; j < NF; ++j)
            bf[j] = *(const short8*)&lsB[(wn + j * 16 + l16) * 32 + ko];
        #pragma unroll
        for (int i = 0; i < 4; ++i)
            #pragma unroll
            for (int j = 0; j < NF; ++j)
                acc[i][j] = __builtin_amdgcn_mfma_f32_16x16x32_bf16(
                    af[i], bf[j], acc[i][j], 0, 0, 0);
    }

    #pragma unroll
    for (int tn = 0; tn < NF; ++tn) {
        const int n = n0 + wn + tn * 16 + l16;
        const float bv = BIAS ? bias[n] : 0.0f;
        #pragma unroll
        for (int tm = 0; tm < 4; ++tm) {
            const int mbase = m0 + wm + tm * 16 + quad * 4;
            #pragma unroll
            for (int rr = 0; rr < 4; ++rr) {
                float v = acc[tm][tn][rr] + bv;
                if (SILU) v = v / (1.0f + __expf(-v));
                const size_t off = (size_t)(mbase + rr) * N + n;
                if (RESID) v += resid[off];
                if constexpr (OUTF32) ((float*)Cm)[off] = v;
                else                  ((ushort*)Cm)[off] = f2b(v);
            }
        }
    }
}

// ---------------- MFMA flash attention, 64 queries/block ----------------
// grid (S/64, B*H), block 256 (4 waves). Wave w owns 16 queries.
// P aliased onto Q's LDS (wave-private strips) -> 27.9 KB -> 5 blocks/CU.
// K/V/mask prefetched into registers one tile ahead (global latency hidden).
// Softmax in exp2 domain; additive pad-mask bias; causal selects diag-only;
// L via ones-MFMA; heavy q-tiles dispatched first.
__global__ __launch_bounds__(256, 5) void attn_kernel(
    const ushort* __restrict__ Qm, const ushort* __restrict__ Km,
    const ushort* __restrict__ Vm, const int* __restrict__ amask,
    ushort* __restrict__ Om, int rs)
{
    __shared__ __align__(16) ushort lsQP[64][72];  // Q staging, then P strips
    __shared__ __align__(16) ushort lsK[64][72];
    __shared__ __align__(16) ushort lsVt[64][72];  // [dim][key]
    __shared__ int lsMk[64];

    const int qt = gridDim.x - 1 - blockIdx.x;     // heaviest first
    const int bh = blockIdx.y;
    const int b = bh >> 4, h = bh & 15;
    const int t = threadIdx.x;
    const int w = t >> 6, lane = t & 63;
    const int quad = lane >> 4, l16 = lane & 15;

    const int q0 = qt * 64;
    const size_t base = ((size_t)b * 2048) * rs + (size_t)h * 64;
    const size_t obase = ((size_t)b * 2048) * 1024 + (size_t)h * 64;

    // stage Q tile (64 x 64)
    #pragma unroll
    for (int it = 0; it < 2; ++it) {
        int idx = it * 256 + t;
        int row = idx >> 3, c8 = (idx & 7) << 3;
        *(int4*)&lsQP[row][c8] =
            *(const int4*)(Qm + base + (size_t)(q0 + row) * rs + c8);
    }
    __syncthreads();

    short8 aq0 = *(const short8*)&lsQP[w * 16 + l16][quad * 8];
    short8 aq1 = *(const short8*)&lsQP[w * 16 + l16][32 + quad * 8];

    short8 ones8;
    #pragma unroll
    for (int i = 0; i < 8; ++i) ones8[i] = (short)0x3F80;  // bf16 1.0

    floatx4 Oacc[4];
    #pragma unroll
    for (int d = 0; d < 4; ++d) Oacc[d] = (floatx4){0.f, 0.f, 0.f, 0.f};
    floatx4 Lacc = (floatx4){0.f, 0.f, 0.f, 0.f};
    float m_i[4] = {-INFINITY, -INFINITY, -INFINITY, -INFINITY};

    const int krow = t >> 3, kc8 = (t & 7) << 3;   // K staging coords
    const int vp = t & 31, vc8 = (t >> 5) << 3;    // V staging coords
    const float scale2 = 0.125f * 1.44269504f;     // softmax in exp2 domain

    // prefetch tile 0
    int4 kr0 = *(const int4*)(Km + base + (size_t)krow * rs + kc8);
    int4 kr1 = *(const int4*)(Km + base + (size_t)(32 + krow) * rs + kc8);
    int4 vr0 = *(const int4*)(Vm + base + (size_t)(2 * vp) * rs + vc8);
    int4 vr1 = *(const int4*)(Vm + base + (size_t)(2 * vp + 1) * rs + vc8);
    int mr = amask[b * 2048 + (t & 63)];

    for (int kt = 0; kt <= qt; ++kt) {
        __syncthreads();   // previous tile's LDS reads complete
        *(int4*)&lsK[krow][kc8] = kr0;
        *(int4*)&lsK[32 + krow][kc8] = kr1;
        {
            const ushort* p0 = (const ushort*)&vr0;
            const ushort* p1 = (const ushort*)&vr1;
            #pragma unroll
            for (int i = 0; i < 8; ++i) {
                uint pk = (uint)p0[i] | ((uint)p1[i] << 16);
                *(uint*)&lsVt[vc8 + i][2 * vp] = pk;
            }
        }
        if (t < 64) lsMk[t] = mr;
        __syncthreads();   // tiles visible

        // prefetch next tile's K/V/mask into registers (overlaps compute)
        if (kt < qt) {
            const int kn = (kt + 1) * 64;
            kr0 = *(const int4*)(Km + base + (size_t)(kn + krow) * rs + kc8);
            kr1 = *(const int4*)(Km + base + (size_t)(kn + 32 + krow) * rs + kc8);
            vr0 = *(const int4*)(Vm + base + (size_t)(kn + 2 * vp) * rs + vc8);
            vr1 = *(const int4*)(Vm + base + (size_t)(kn + 2 * vp + 1) * rs + vc8);
            mr = amask[b * 2048 + kn + (t & 63)];
        }

        // ---- QK^T ----
        floatx4 sa[4];
        #pragma unroll
        for (int j = 0; j < 4; ++j) {
            short8 bk0 = *(const short8*)&lsK[j * 16 + l16][quad * 8];
            short8 bk1 = *(const short8*)&lsK[j * 16 + l16][32 + quad * 8];
            floatx4 z = (floatx4){0.f, 0.f, 0.f, 0.f};
            z = __builtin_amdgcn_mfma_f32_16x16x32_bf16(aq0, bk0, z, 0, 0, 0);
            sa[j] = __builtin_amdgcn_mfma_f32_16x16x32_bf16(aq1, bk1, z, 0, 0, 0);
        }

        float kb[4];
        #pragma unroll
        for (int j = 0; j < 4; ++j)
            kb[j] = (lsMk[j * 16 + l16] == 1) ? 0.f : -INFINITY;
        const bool diag = (kt == qt);

        // ---- online softmax (per C-layout row), P -> wave-private LDS ----
        float al[4];
        #pragma unroll
        for (int rr = 0; rr < 4; ++rr) {
            const int qrow = w * 16 + quad * 4 + rr;
            float sv[4];
            float mxv = -INFINITY;
            #pragma unroll
            for (int j = 0; j < 4; ++j) {
                float v = sa[j][rr] * scale2 + kb[j];
                if (diag) v = (j * 16 + l16 <= qrow) ? v : -INFINITY;
                sv[j] = v;
                mxv = fmaxf(mxv, v);
            }
            mxv = dpp_max16(mxv);
            const float m_new = fmaxf(m_i[rr], mxv);
            al[rr] = exp2f(m_i[rr] - m_new);
            #pragma unroll
            for (int j = 0; j < 4; ++j) {
                const float p = exp2f(sv[j] - m_new);
                lsQP[w * 16 + quad * 4 + rr][j * 16 + l16] =
                    (ushort)(__float_as_uint(p) >> 16);   // truncating bf16
            }
            m_i[rr] = m_new;
        }
        #pragma unroll
        for (int rr = 0; rr < 4; ++rr) {
            #pragma unroll
            for (int d = 0; d < 4; ++d) Oacc[d][rr] *= al[rr];
            Lacc[rr] *= al[rr];
        }

        // ---- PV + L ----
        short8 ap0 = *(const short8*)&lsQP[w * 16 + l16][quad * 8];
        short8 ap1 = *(const short8*)&lsQP[w * 16 + l16][32 + quad * 8];
        #pragma unroll
        for (int d = 0; d < 4; ++d) {
            short8 bv0 = *(const short8*)&lsVt[d * 16 + l16][quad * 8];
            short8 bv1 = *(const short8*)&lsVt[d * 16 + l16][32 + quad * 8];
            Oacc[d] = __builtin_amdgcn_mfma_f32_16x16x32_bf16(ap0, bv0, Oacc[d], 0, 0, 0);
            Oacc[d] = __builtin_amdgcn_mfma_f32_16x16x32_bf16(ap1, bv1, Oacc[d], 0, 0, 0);
        }
        Lacc = __builtin_amdgcn_mfma_f32_16x16x32_bf16(ap0, ones8, Lacc, 0, 0, 0);
        Lacc = __builtin_amdgcn_mfma_f32_16x16x32_bf16(ap1, ones8, Lacc, 0, 0, 0);
    }

    #pragma unroll
    for (int rr = 0; rr < 4; ++rr) {
        const float inv = 1.0f / Lacc[rr];
        const int row = q0 + w * 16 + quad * 4 + rr;
        ushort* op = Om + obase + (size_t)row * 1024;
        #pragma unroll
        for (int d = 0; d < 4; ++d)
            op[d * 16 + l16] = f2b(Oacc[d][rr] * inv);
    }
}

// ---------------- driver ----------------
// ws peak 72 MiB:
//   phase 1: xa [0,16) | qkvb [16,64) | Wqkv_t [64,70) | Wo_t [70,72)
//   phase 2: W1_t [0,8) W2_t [8,16) | yb [16,32) | hb chunk [32,64)
extern "C" void kernel_launch(void* const* d_in, const int* in_sizes, int n_in,
                              void* d_out, int out_size, void* d_ws, size_t ws_size,
                              hipStream_t stream) {
    const float* hidden = (const float*)d_in[0];
    const int*   amask  = (const int*)d_in[1];
    const float* Wq  = (const float*)d_in[2];
    const float* Wk  = (const float*)d_in[3];
    const float* Wv  = (const float*)d_in[4];
    const float* Wo  = (const float*)d_in[5];
    const float* l1g = (const float*)d_in[6];
    const float* l1b = (const float*)d_in[7];
    const float* W1  = (const float*)d_in[8];
    const float* b1  = (const float*)d_in[9];
    const float* W2  = (const float*)d_in[10];
    const float* b2  = (const float*)d_in[11];
    const float* l2g = (const float*)d_in[12];
    const float* l2b = (const float*)d_in[13];

    const int M = 8192;
    const size_t MB = 1048576;
    char* ws = (char*)d_ws;
    ushort* xa    = (ushort*)(ws);
    ushort* qkvb  = (ushort*)(ws + 16 * MB);
    ushort* Wqkvt = (ushort*)(ws + 64 * MB);
    ushort* Wot   = (ushort*)(ws + 70 * MB);
    ushort* W1t   = (ushort*)(ws);
    ushort* W2t   = (ushort*)(ws + 8 * MB);
    ushort* yb    = (ushort*)(ws + 16 * MB);
    ushort* hbc   = (ushort*)(ws + 32 * MB);
    float*  x2    = (float*)d_out;

    cvt_t_kernel<<<dim3(32, 32), 256, 0, stream>>>(Wq, Wqkvt, 1024, 1024);
    cvt_t_kernel<<<dim3(32, 32), 256, 0, stream>>>(Wk, Wqkvt + (size_t)1024 * 1024, 1024, 1024);
    cvt_t_kernel<<<dim3(32, 32), 256, 0, stream>>>(Wv, Wqkvt + (size_t)2048 * 1024, 1024, 1024);
    cvt_t_kernel<<<dim3(32, 32), 256, 0, stream>>>(Wo, Wot, 1024, 1024);

    ln_kernel<<<M, 256, 0, stream>>>(hidden, l1g, l1b, xa);
    gemm_bt_kernel<128, false, false, false, false><<<dim3(24, 64), 256, 0, stream>>>(
        xa, Wqkvt, nullptr, nullptr, qkvb, M, 3072, 1024);
    attn_kernel<<<dim3(32, 64), 256, 0, stream>>>(
        qkvb, qkvb + 1024, qkvb + 2048, amask, xa, 3072);
    gemm_bt_kernel<64, false, false, true, true><<<dim3(16, 64), 256, 0, stream>>>(
        xa, Wot, nullptr, hidden, x2, M, 1024, 1024);

    cvt_t_kernel<<<dim3(128, 32), 256, 0, stream>>>(W1, W1t, 1024, 4096);
    cvt_t_kernel<<<dim3(32, 128), 256, 0, stream>>>(W2, W2t, 4096, 1024);

    ln_kernel<<<M, 256, 0, stream>>>(x2, l2g, l2b, yb);
    for (int mc = 0; mc < 2; ++mc) {
        const size_t off = (size_t)mc * 4096 * 1024;
        gemm_bt_kernel<128, true, true, false, false><<<dim3(32, 32), 256, 0, stream>>>(
            yb + off, W1t, b1, nullptr, hbc, 4096, 4096, 1024);
        gemm_bt_kernel<64, true, false, true, true><<<dim3(16, 32), 256, 0, stream>>>(
            hbc, W2t, b2, x2 + off, (void*)(x2 + off), 4096, 1024, 4096);
    }
}